// Round 1
// baseline (345.409 us; speedup 1.0000x reference)
//
#include <hip/hip_runtime.h>
#include <math.h>

#define NBATCH 32
#define TOPK 50
#define NCH 225
#define MAXM 25600

// monotone float->uint key: preserves ordering, larger float -> larger key
__device__ __forceinline__ unsigned int f2key(float f) {
    unsigned int u = __float_as_uint(f);
    return (u & 0x80000000u) ? ~u : (u | 0x80000000u);
}
__device__ __forceinline__ float key2f(unsigned int k) {
    unsigned int u = (k & 0x80000000u) ? (k ^ 0x80000000u) : ~k;
    return __uint_as_float(u);
}

struct Args {
    const float* conf[3];
    const float* obj[3];
    const float* act[3];
    const float* rel[3];
    const float* intp[3];
    const float* reg[3];
    float* out;
};

__global__ __launch_bounds__(256)
void yowo_topk_kernel(Args a) {
    __shared__ unsigned int s_keys[MAXM];          // 100 KB
    __shared__ unsigned long long s_wred[4];
    __shared__ unsigned long long s_winner;
    __shared__ unsigned int s_selKey[TOPK];
    __shared__ unsigned int s_selIdx[TOPK];

    const int tid = threadIdx.x;
    const int lvl = blockIdx.x >> 5;   // blockIdx.x / 32
    const int b   = blockIdx.x & 31;

    const int M      = (lvl == 0) ? 25600 : (lvl == 1) ? 6400 : 1600;
    const int stride = 8 << lvl;
    const int n      = 1280 / stride;

    const float* confp = a.conf[lvl] + (size_t)b * M;

    // ---- Phase A: stage bit-keys into LDS, track per-thread local max ----
    unsigned int lkey = 0u;
    int lidx = 0;
    for (int m = tid; m < M; m += 256) {
        unsigned int k = f2key(confp[m]);
        s_keys[m] = k;
        if (k > lkey) { lkey = k; lidx = m; }   // strict > keeps smallest idx
    }
    __syncthreads();

    const int wid  = tid >> 6;
    const int lane = tid & 63;

    for (int i = 0; i < TOPK; ++i) {
        // pack so max-of-pack == (max key, then min index)
        unsigned long long p =
            ((unsigned long long)lkey << 32) | (unsigned int)(~(unsigned int)lidx);
        #pragma unroll
        for (int off = 32; off > 0; off >>= 1) {
            unsigned long long q = __shfl_xor(p, off, 64);
            if (q > p) p = q;
        }
        if (lane == 0) s_wred[wid] = p;
        __syncthreads();
        if (tid == 0) {
            unsigned long long w = s_wred[0];
            #pragma unroll
            for (int j = 1; j < 4; ++j) if (s_wred[j] > w) w = s_wred[j];
            s_winner = w;
            s_selKey[i] = (unsigned int)(w >> 32);
            s_selIdx[i] = ~(unsigned int)w;
        }
        __syncthreads();
        const unsigned long long w = s_winner;
        const unsigned int widx = ~(unsigned int)w;
        // owner thread removes the winner and rescans its strided slice
        if (tid == (int)(widx & 255u)) {
            s_keys[widx] = 0u;
            lkey = 0u; lidx = 0;
            for (int m = tid; m < M; m += 256) {
                unsigned int k2 = s_keys[m];
                if (k2 > lkey) { lkey = k2; lidx = m; }
            }
        }
    }
    __syncthreads();

    // ---- Phase B: write the 50 output rows (225 channels each) ----
    const float* objp = a.obj[lvl];
    const float* actp = a.act[lvl];
    const float* relp = a.rel[lvl];
    const float* intp = a.intp[lvl];
    const float* regp = a.reg[lvl];

    for (int k = wid; k < TOPK; k += 4) {
        const unsigned int idx = s_selIdx[k];
        const float logit = key2f(s_selKey[k]);
        const float sc = 1.0f / (1.0f + expf(-logit));
        const float keep = (sc > 0.05f) ? 1.0f : 0.0f;

        float* orow = a.out + ((size_t)b * 150 + (size_t)lvl * TOPK + k) * NCH;
        const size_t rbase = (size_t)b * M + idx;

        // obj softmax over 36 classes (full-wave shuffle sum; lanes>=36 add 0)
        float e = 0.0f;
        if (lane < 36) e = expf(objp[rbase * 36 + lane]);
        float s = e;
        #pragma unroll
        for (int off = 32; off > 0; off >>= 1) s += __shfl_xor(s, off, 64);
        if (lane < 36) orow[6 + lane] = keep * (e / s);

        // act sigmoid (157)
        for (int c = lane; c < 157; c += 64) {
            float x = actp[rbase * 157 + c];
            orow[42 + c] = keep / (1.0f + expf(-x));
        }
        // rel sigmoid (26)
        if (lane < 26) {
            float x = relp[rbase * 26 + lane];
            orow[199 + lane] = keep / (1.0f + expf(-x));
        }
        // conf, inter, box
        if (lane == 0) {
            orow[4] = keep * sc;
            float xi = intp[rbase];
            orow[5] = keep / (1.0f + expf(-xi));
            const float r0 = regp[rbase * 4 + 0];
            const float r1 = regp[rbase * 4 + 1];
            const float r2 = regp[rbase * 4 + 2];
            const float r3 = regp[rbase * 4 + 3];
            const int yy = (int)idx / n;
            const int xx = (int)idx % n;
            const float fs = (float)stride;
            const float cx = (xx + 0.5f) * fs + r0 * fs;
            const float cy = (yy + 0.5f) * fs + r1 * fs;
            const float w2 = 0.5f * expf(r2) * fs;
            const float h2 = 0.5f * expf(r3) * fs;
            orow[0] = keep * (cx - w2);
            orow[1] = keep * (cy - h2);
            orow[2] = keep * (cx + w2);
            orow[3] = keep * (cy + h2);
        }
    }
}

extern "C" void kernel_launch(void* const* d_in, const int* in_sizes, int n_in,
                              void* d_out, int out_size, void* d_ws, size_t ws_size,
                              hipStream_t stream) {
    (void)in_sizes; (void)n_in; (void)d_ws; (void)ws_size; (void)out_size;
    Args a;
    for (int l = 0; l < 3; ++l) {
        a.conf[l] = (const float*)d_in[l * 6 + 0];
        a.obj[l]  = (const float*)d_in[l * 6 + 1];
        a.act[l]  = (const float*)d_in[l * 6 + 2];
        a.rel[l]  = (const float*)d_in[l * 6 + 3];
        a.intp[l] = (const float*)d_in[l * 6 + 4];
        a.reg[l]  = (const float*)d_in[l * 6 + 5];
    }
    a.out = (float*)d_out;
    hipLaunchKernelGGL(yowo_topk_kernel, dim3(96), dim3(256), 0, stream, a);
}

// Round 2
// 61.597 us; speedup vs baseline: 5.6076x; 5.6076x over previous
//
#include <hip/hip_runtime.h>
#include <math.h>

#define TOPK 50
#define NCH 225
#define MAXM 25600
#define CAP 256

// monotone float->uint key: preserves ordering, larger float -> larger key
__device__ __forceinline__ unsigned int f2key(float f) {
    unsigned int u = __float_as_uint(f);
    return (u & 0x80000000u) ? ~u : (u | 0x80000000u);
}
__device__ __forceinline__ float key2f(unsigned int k) {
    unsigned int u = (k & 0x80000000u) ? (k ^ 0x80000000u) : ~k;
    return __uint_as_float(u);
}

struct Args {
    const float* conf[3];
    const float* obj[3];
    const float* act[3];
    const float* rel[3];
    const float* intp[3];
    const float* reg[3];
    float* out;
};

__global__ __launch_bounds__(256)
void yowo_topk_kernel(Args a) {
    __shared__ unsigned int s_keys[MAXM];        // 100 KB
    __shared__ unsigned int s_hist[256];
    __shared__ unsigned int s_scan[256];
    __shared__ unsigned int s_candKey[CAP];
    __shared__ unsigned int s_candIdx[CAP];
    __shared__ unsigned int s_selKey[TOPK];
    __shared__ unsigned int s_selIdx[TOPK];
    __shared__ unsigned int s_cnt;
    __shared__ unsigned int s_selBin, s_newNeed;
    __shared__ unsigned long long s_wred[4];
    __shared__ unsigned long long s_winner;

    const int tid = threadIdx.x;
    const int lvl = blockIdx.x >> 5;
    const int b   = blockIdx.x & 31;

    const int M      = (lvl == 0) ? 25600 : (lvl == 1) ? 6400 : 1600;
    const int stride = 8 << lvl;
    const int n      = 1280 / stride;

    const float* confp = a.conf[lvl] + (size_t)b * M;

    // ---- Pass 1: global -> keys in LDS + histogram of top byte ----
    s_hist[tid] = 0u;
    __syncthreads();
    for (int m = tid * 4; m < M; m += 1024) {
        float4 c4 = *(const float4*)(confp + m);
        unsigned int k0 = f2key(c4.x), k1 = f2key(c4.y),
                     k2 = f2key(c4.z), k3 = f2key(c4.w);
        s_keys[m]     = k0;
        s_keys[m + 1] = k1;
        s_keys[m + 2] = k2;
        s_keys[m + 3] = k3;
        atomicAdd(&s_hist[k0 >> 24], 1u);
        atomicAdd(&s_hist[k1 >> 24], 1u);
        atomicAdd(&s_hist[k2 >> 24], 1u);
        atomicAdd(&s_hist[k3 >> 24], 1u);
    }
    __syncthreads();

    // ---- Radix select: find exact 50th-largest key, byte by byte ----
    unsigned int prefix = 0u;
    unsigned int need = TOPK;
    for (int pass = 0; pass < 4; ++pass) {
        const int shift = 24 - 8 * pass;
        // suffix sums of hist (incl[t] = sum hist[t..255]) via Hillis-Steele
        unsigned int v = s_hist[tid];
        s_scan[tid] = v;
        __syncthreads();
        for (int d = 1; d < 256; d <<= 1) {
            unsigned int add = (tid + d < 256) ? s_scan[tid + d] : 0u;
            __syncthreads();
            s_scan[tid] += add;
            __syncthreads();
        }
        unsigned int incl = s_scan[tid];
        unsigned int excl = incl - v;
        if (excl < need && incl >= need) {   // unique crossing bin
            s_selBin = (unsigned int)tid;
            s_newNeed = need - excl;
        }
        __syncthreads();
        prefix |= (s_selBin << shift);
        need = s_newNeed;
        if (pass == 3) break;
        __syncthreads();
        // rebuild histogram of next byte among keys matching current prefix
        s_hist[tid] = 0u;
        __syncthreads();
        const int nshift = shift - 8;
        const unsigned int hi = prefix >> shift;
        for (int m = tid * 4; m < M; m += 1024) {
            uint4 k4 = *(const uint4*)(&s_keys[m]);
            if ((k4.x >> shift) == hi) atomicAdd(&s_hist[(k4.x >> nshift) & 255u], 1u);
            if ((k4.y >> shift) == hi) atomicAdd(&s_hist[(k4.y >> nshift) & 255u], 1u);
            if ((k4.z >> shift) == hi) atomicAdd(&s_hist[(k4.z >> nshift) & 255u], 1u);
            if ((k4.w >> shift) == hi) atomicAdd(&s_hist[(k4.w >> nshift) & 255u], 1u);
        }
        __syncthreads();
    }

    // ---- Compact all keys >= kth key ----
    if (tid == 0) s_cnt = 0u;
    __syncthreads();
    for (int m = tid * 4; m < M; m += 1024) {
        uint4 k4 = *(const uint4*)(&s_keys[m]);
        #pragma unroll
        for (int j = 0; j < 4; ++j) {
            unsigned int k = (j == 0) ? k4.x : (j == 1) ? k4.y : (j == 2) ? k4.z : k4.w;
            if (k >= prefix) {
                unsigned int pos = atomicAdd(&s_cnt, 1u);
                if (pos < CAP) { s_candKey[pos] = k; s_candIdx[pos] = (unsigned int)(m + j); }
            }
        }
    }
    __syncthreads();
    const unsigned int cnt = s_cnt;

    if (cnt <= CAP) {
        // ---- Rank-sort candidates by (key desc, idx asc) ----
        if (tid < (int)cnt) {
            unsigned int k = s_candKey[tid], idx = s_candIdx[tid];
            unsigned long long p =
                ((unsigned long long)k << 32) | (unsigned int)(~idx);
            int rank = 0;
            for (unsigned int j = 0; j < cnt; ++j) {
                unsigned long long q =
                    ((unsigned long long)s_candKey[j] << 32) |
                    (unsigned int)(~s_candIdx[j]);
                rank += (q > p) ? 1 : 0;
            }
            if (rank < TOPK) { s_selKey[rank] = k; s_selIdx[rank] = idx; }
        }
    } else {
        // ---- Fallback (massive ties; never expected): full-block argmax x50 ----
        for (int i = 0; i < TOPK; ++i) {
            unsigned long long p = 0ull;
            for (int m = tid; m < M; m += 256) {
                unsigned int k = s_keys[m];
                if (k) {
                    unsigned long long pk =
                        ((unsigned long long)k << 32) | (unsigned int)(~(unsigned int)m);
                    if (pk > p) p = pk;
                }
            }
            #pragma unroll
            for (int off = 32; off > 0; off >>= 1) {
                unsigned long long q = __shfl_xor(p, off, 64);
                if (q > p) p = q;
            }
            if ((tid & 63) == 0) s_wred[tid >> 6] = p;
            __syncthreads();
            if (tid == 0) {
                unsigned long long w = s_wred[0];
                #pragma unroll
                for (int j = 1; j < 4; ++j) if (s_wred[j] > w) w = s_wred[j];
                s_winner = w;
            }
            __syncthreads();
            const unsigned long long w = s_winner;
            const unsigned int widx = ~(unsigned int)w;
            if (tid == 0) { s_selKey[i] = (unsigned int)(w >> 32); s_selIdx[i] = widx; }
            if (tid == (int)(widx & 255u)) s_keys[widx] = 0u;
            __syncthreads();
        }
    }
    __syncthreads();

    // ---- Phase B: write the 50 output rows (225 channels each) ----
    const int wid  = tid >> 6;
    const int lane = tid & 63;
    const float* objp = a.obj[lvl];
    const float* actp = a.act[lvl];
    const float* relp = a.rel[lvl];
    const float* intp = a.intp[lvl];
    const float* regp = a.reg[lvl];

    for (int k = wid; k < TOPK; k += 4) {
        const unsigned int idx = s_selIdx[k];
        const float logit = key2f(s_selKey[k]);
        const float sc = 1.0f / (1.0f + expf(-logit));
        const float keep = (sc > 0.05f) ? 1.0f : 0.0f;

        float* orow = a.out + ((size_t)b * 150 + (size_t)lvl * TOPK + k) * NCH;
        const size_t rbase = (size_t)b * M + idx;

        // obj softmax over 36 classes (full-wave shuffle sum; lanes>=36 add 0)
        float e = 0.0f;
        if (lane < 36) e = expf(objp[rbase * 36 + lane]);
        float s = e;
        #pragma unroll
        for (int off = 32; off > 0; off >>= 1) s += __shfl_xor(s, off, 64);
        if (lane < 36) orow[6 + lane] = keep * (e / s);

        // act sigmoid (157)
        for (int c = lane; c < 157; c += 64) {
            float x = actp[rbase * 157 + c];
            orow[42 + c] = keep / (1.0f + expf(-x));
        }
        // rel sigmoid (26)
        if (lane < 26) {
            float x = relp[rbase * 26 + lane];
            orow[199 + lane] = keep / (1.0f + expf(-x));
        }
        // conf, inter, box
        if (lane == 0) {
            orow[4] = keep * sc;
            float xi = intp[rbase];
            orow[5] = keep / (1.0f + expf(-xi));
            const float r0 = regp[rbase * 4 + 0];
            const float r1 = regp[rbase * 4 + 1];
            const float r2 = regp[rbase * 4 + 2];
            const float r3 = regp[rbase * 4 + 3];
            const int yy = (int)idx / n;
            const int xx = (int)idx % n;
            const float fs = (float)stride;
            const float cx = (xx + 0.5f) * fs + r0 * fs;
            const float cy = (yy + 0.5f) * fs + r1 * fs;
            const float w2 = 0.5f * expf(r2) * fs;
            const float h2 = 0.5f * expf(r3) * fs;
            orow[0] = keep * (cx - w2);
            orow[1] = keep * (cy - h2);
            orow[2] = keep * (cx + w2);
            orow[3] = keep * (cy + h2);
        }
    }
}

extern "C" void kernel_launch(void* const* d_in, const int* in_sizes, int n_in,
                              void* d_out, int out_size, void* d_ws, size_t ws_size,
                              hipStream_t stream) {
    (void)in_sizes; (void)n_in; (void)d_ws; (void)ws_size; (void)out_size;
    Args a;
    for (int l = 0; l < 3; ++l) {
        a.conf[l] = (const float*)d_in[l * 6 + 0];
        a.obj[l]  = (const float*)d_in[l * 6 + 1];
        a.act[l]  = (const float*)d_in[l * 6 + 2];
        a.rel[l]  = (const float*)d_in[l * 6 + 3];
        a.intp[l] = (const float*)d_in[l * 6 + 4];
        a.reg[l]  = (const float*)d_in[l * 6 + 5];
    }
    a.out = (float*)d_out;
    hipLaunchKernelGGL(yowo_topk_kernel, dim3(96), dim3(256), 0, stream, a);
}

// Round 3
// 34.124 us; speedup vs baseline: 10.1220x; 1.8051x over previous
//
#include <hip/hip_runtime.h>
#include <math.h>

#define TOPK 50
#define NCH 225
#define NBINS 16384
#define BINS_PER_T 64
#define CAP 1024

// monotone float->uint key: preserves ordering, larger float -> larger key
__device__ __forceinline__ unsigned int f2key(float f) {
    unsigned int u = __float_as_uint(f);
    return (u & 0x80000000u) ? ~u : (u | 0x80000000u);
}
__device__ __forceinline__ float key2f(unsigned int k) {
    unsigned int u = (k & 0x80000000u) ? (k ^ 0x80000000u) : ~k;
    return __uint_as_float(u);
}

struct ArgsA { const float* conf[3]; uint2* sel; };

struct ArgsB {
    const float* obj[3];
    const float* act[3];
    const float* rel[3];
    const float* intp[3];
    const float* reg[3];
    const uint2* sel;
    float* out;
};

// ---------------- Kernel A: exact top-50 select per (lvl, batch) ----------------
__global__ __launch_bounds__(256)
void yowo_select_kernel(ArgsA a) {
    __shared__ unsigned int s_hist[NBINS];        // 64 KB
    __shared__ unsigned int s_scan[256];
    __shared__ unsigned int s_candKey[CAP];
    __shared__ unsigned int s_candIdx[CAP];
    __shared__ unsigned int s_selKey[TOPK];
    __shared__ unsigned int s_selIdx[TOPK];
    __shared__ unsigned int s_cnt;
    __shared__ unsigned int s_bin, s_cntGe;
    __shared__ unsigned long long s_wred[4];
    __shared__ unsigned long long s_prev;

    const int tid = threadIdx.x;
    const int lvl = blockIdx.x >> 5;
    const int b   = blockIdx.x & 31;
    const int M   = (lvl == 0) ? 25600 : (lvl == 1) ? 6400 : 1600;
    const float* confp = a.conf[lvl] + (size_t)b * M;

    // zero histogram
    for (int i = tid * 4; i < NBINS; i += 1024)
        *(uint4*)&s_hist[i] = make_uint4(0u, 0u, 0u, 0u);
    __syncthreads();

    // pass 1: 14-bit histogram of top bits of the monotone key
    for (int m = tid * 4; m < M; m += 1024) {
        float4 c4 = *(const float4*)(confp + m);
        atomicAdd(&s_hist[f2key(c4.x) >> 18], 1u);
        atomicAdd(&s_hist[f2key(c4.y) >> 18], 1u);
        atomicAdd(&s_hist[f2key(c4.z) >> 18], 1u);
        atomicAdd(&s_hist[f2key(c4.w) >> 18], 1u);
    }
    __syncthreads();

    // hierarchical suffix scan: in-chunk suffix (64 bins/thread), then 256-part scan
    const int base = tid * BINS_PER_T;
    unsigned int acc = 0u;
    for (int j = BINS_PER_T - 1; j >= 0; --j) {
        acc += s_hist[base + j];
        s_hist[base + j] = acc;            // in-place: suffix within chunk
    }
    s_scan[tid] = acc;                     // chunk total
    __syncthreads();
    for (int d = 1; d < 256; d <<= 1) {
        unsigned int add = (tid + d < 256) ? s_scan[tid + d] : 0u;
        __syncthreads();
        s_scan[tid] += add;                // inclusive suffix over chunks
        __syncthreads();
    }
    const unsigned int right = (tid < 255) ? s_scan[tid + 1] : 0u;  // sum of chunks > tid

    // crossing bin lives in my chunk iff S(t) >= 50 > right(t)
    if (s_scan[tid] >= TOPK && right < TOPK) {
        for (int j = 0; j < BINS_PER_T; ++j) {
            unsigned int cge  = s_hist[base + j] + right;
            unsigned int cgen = ((j < BINS_PER_T - 1) ? s_hist[base + j + 1] : 0u) + right;
            if (cge >= TOPK && cgen < TOPK) { s_bin = (unsigned int)(base + j); s_cntGe = cge; }
        }
    }
    __syncthreads();

    const unsigned int cntGe = s_cntGe;
    const unsigned int thr   = s_bin << 18;

    if (cntGe <= CAP) {
        // compact all keys >= thr (re-read conf; L2-hot)
        if (tid == 0) s_cnt = 0u;
        __syncthreads();
        for (int m = tid * 4; m < M; m += 1024) {
            float4 c4 = *(const float4*)(confp + m);
            unsigned int ks[4] = { f2key(c4.x), f2key(c4.y), f2key(c4.z), f2key(c4.w) };
            #pragma unroll
            for (int j = 0; j < 4; ++j) {
                if (ks[j] >= thr) {
                    unsigned int pos = atomicAdd(&s_cnt, 1u);
                    s_candKey[pos] = ks[j];
                    s_candIdx[pos] = (unsigned int)(m + j);
                }
            }
        }
        __syncthreads();
        const unsigned int cnt = s_cnt;
        // rank-sort by (key desc, idx asc)
        for (int t = tid; t < (int)cnt; t += 256) {
            const unsigned long long p =
                ((unsigned long long)s_candKey[t] << 32) | (unsigned int)(~s_candIdx[t]);
            int rank = 0;
            for (unsigned int j = 0; j < cnt; ++j) {
                const unsigned long long q =
                    ((unsigned long long)s_candKey[j] << 32) | (unsigned int)(~s_candIdx[j]);
                rank += (q > p) ? 1 : 0;
            }
            if (rank < TOPK) { s_selKey[rank] = s_candKey[t]; s_selIdx[rank] = s_candIdx[t]; }
        }
        __syncthreads();
    } else {
        // exact fallback (massive key ties; never expected): 50 descending packed-max passes
        unsigned long long prev = 0xFFFFFFFFFFFFFFFFull;
        for (int i = 0; i < TOPK; ++i) {
            unsigned long long p = 0ull;
            for (int m = tid; m < M; m += 256) {
                unsigned long long pk =
                    ((unsigned long long)f2key(confp[m]) << 32) |
                    (unsigned int)(~(unsigned int)m);
                if (pk < prev && pk > p) p = pk;
            }
            #pragma unroll
            for (int off = 32; off > 0; off >>= 1) {
                unsigned long long q = __shfl_xor(p, off, 64);
                if (q > p) p = q;
            }
            if ((tid & 63) == 0) s_wred[tid >> 6] = p;
            __syncthreads();
            if (tid == 0) {
                unsigned long long w = s_wred[0];
                #pragma unroll
                for (int j = 1; j < 4; ++j) if (s_wred[j] > w) w = s_wred[j];
                s_prev = w;
                s_selKey[i] = (unsigned int)(w >> 32);
                s_selIdx[i] = ~(unsigned int)w;
            }
            __syncthreads();
            prev = s_prev;
            __syncthreads();
        }
    }

    if (tid < TOPK)
        a.sel[(size_t)blockIdx.x * TOPK + tid] = make_uint2(s_selKey[tid], s_selIdx[tid]);
}

// ---------------- Kernel B: one wave per output row ----------------
__global__ __launch_bounds__(256)
void yowo_write_kernel(ArgsB a) {
    const int tid  = threadIdx.x;
    const int wid  = tid >> 6;
    const int lane = tid & 63;
    const int row  = blockIdx.x * 4 + wid;          // 0..4799
    const int b    = row / 150;
    const int w    = row % 150;
    const int lvl  = w / 50;
    const int k    = w % 50;

    const int M      = (lvl == 0) ? 25600 : (lvl == 1) ? 6400 : 1600;
    const int stride = 8 << lvl;
    const int n      = 1280 / stride;

    const uint2 sel = a.sel[(size_t)(lvl * 32 + b) * TOPK + k];
    const unsigned int idx = sel.y;
    const float logit = key2f(sel.x);
    const float sc    = 1.0f / (1.0f + expf(-logit));
    const float keep  = (sc > 0.05f) ? 1.0f : 0.0f;

    float* orow = a.out + ((size_t)b * 150 + w) * NCH;
    const size_t rbase = (size_t)b * M + idx;

    // obj softmax over 36 classes (full-wave shuffle sum; lanes>=36 add 0)
    float e = 0.0f;
    if (lane < 36) e = expf(a.obj[lvl][rbase * 36 + lane]);
    float s = e;
    #pragma unroll
    for (int off = 32; off > 0; off >>= 1) s += __shfl_xor(s, off, 64);
    if (lane < 36) orow[6 + lane] = keep * (e / s);

    // act sigmoid (157)
    for (int c = lane; c < 157; c += 64) {
        float x = a.act[lvl][rbase * 157 + c];
        orow[42 + c] = keep / (1.0f + expf(-x));
    }
    // rel sigmoid (26)
    if (lane < 26) {
        float x = a.rel[lvl][rbase * 26 + lane];
        orow[199 + lane] = keep / (1.0f + expf(-x));
    }
    // conf, inter, box
    if (lane == 0) {
        orow[4] = keep * sc;
        float xi = a.intp[lvl][rbase];
        orow[5] = keep / (1.0f + expf(-xi));
        const float r0 = a.reg[lvl][rbase * 4 + 0];
        const float r1 = a.reg[lvl][rbase * 4 + 1];
        const float r2 = a.reg[lvl][rbase * 4 + 2];
        const float r3 = a.reg[lvl][rbase * 4 + 3];
        const int yy = (int)idx / n;
        const int xx = (int)idx % n;
        const float fs = (float)stride;
        const float cx = (xx + 0.5f) * fs + r0 * fs;
        const float cy = (yy + 0.5f) * fs + r1 * fs;
        const float w2 = 0.5f * expf(r2) * fs;
        const float h2 = 0.5f * expf(r3) * fs;
        orow[0] = keep * (cx - w2);
        orow[1] = keep * (cy - h2);
        orow[2] = keep * (cx + w2);
        orow[3] = keep * (cy + h2);
    }
}

extern "C" void kernel_launch(void* const* d_in, const int* in_sizes, int n_in,
                              void* d_out, int out_size, void* d_ws, size_t ws_size,
                              hipStream_t stream) {
    (void)in_sizes; (void)n_in; (void)out_size; (void)ws_size;
    uint2* sel = (uint2*)d_ws;                 // 96*50*8 = 38400 B

    ArgsA aa;
    ArgsB ab;
    for (int l = 0; l < 3; ++l) {
        aa.conf[l] = (const float*)d_in[l * 6 + 0];
        ab.obj[l]  = (const float*)d_in[l * 6 + 1];
        ab.act[l]  = (const float*)d_in[l * 6 + 2];
        ab.rel[l]  = (const float*)d_in[l * 6 + 3];
        ab.intp[l] = (const float*)d_in[l * 6 + 4];
        ab.reg[l]  = (const float*)d_in[l * 6 + 5];
    }
    aa.sel = sel;
    ab.sel = sel;
    ab.out = (float*)d_out;

    hipLaunchKernelGGL(yowo_select_kernel, dim3(96), dim3(256), 0, stream, aa);
    hipLaunchKernelGGL(yowo_write_kernel, dim3(1200), dim3(256), 0, stream, ab);
}

// Round 4
// 20.845 us; speedup vs baseline: 16.5706x; 1.6371x over previous
//
#include <hip/hip_runtime.h>
#include <math.h>

#define TOPK 50
#define NCH 225
#define NBINS 16384
#define BPT 16              // bins per thread chunk (16384 / 1024)
#define PADC 17             // padded chunk stride (coprime with 32 banks)
#define CAP 1024
#define NT 1024
#define NW 16
#define MAXIT 7             // ceil(25600 / 4096)

// monotone float->uint key: preserves ordering, larger float -> larger key
__device__ __forceinline__ unsigned int f2key(float f) {
    unsigned int u = __float_as_uint(f);
    return (u & 0x80000000u) ? ~u : (u | 0x80000000u);
}
__device__ __forceinline__ float key2f(unsigned int k) {
    unsigned int u = (k & 0x80000000u) ? (k ^ 0x80000000u) : ~k;
    return __uint_as_float(u);
}
// padded LDS address for a bin
__device__ __forceinline__ int pbin(unsigned int bin) {
    return (int)((bin >> 4) * PADC + (bin & 15u));
}

struct Args {
    const float* conf[3];
    const float* obj[3];
    const float* act[3];
    const float* rel[3];
    const float* intp[3];
    const float* reg[3];
    float* out;
};

__global__ __launch_bounds__(NT)
void yowo_fused_kernel(Args a) {
    __shared__ unsigned int s_hist[NT * PADC];     // 68 KB, pad-17 layout
    __shared__ unsigned int s_wtot[NW];
    __shared__ unsigned int s_woff[NW];
    __shared__ unsigned int s_candKey[CAP];
    __shared__ unsigned int s_candIdx[CAP];
    __shared__ unsigned int s_selKey[TOPK];
    __shared__ unsigned int s_selIdx[TOPK];
    __shared__ unsigned int s_cnt;
    __shared__ unsigned int s_bin, s_cntGe;
    __shared__ unsigned long long s_wred[NW];
    __shared__ unsigned long long s_prev;

    const int tid  = threadIdx.x;
    const int wid  = tid >> 6;
    const int lane = tid & 63;
    const int lvl  = blockIdx.x >> 5;
    const int b    = blockIdx.x & 31;
    const int M    = (lvl == 0) ? 25600 : (lvl == 1) ? 6400 : 1600;
    const int stride = 8 << lvl;
    const int n    = 1280 / stride;
    const float* confp = a.conf[lvl] + (size_t)b * M;

    // ---- zero padded histogram (per-thread contiguous chunk, stride-17: conflict-free)
    {
        const int zb = tid * PADC;
        #pragma unroll
        for (int j = 0; j < PADC; ++j) s_hist[zb + j] = 0u;
    }
    __syncthreads();

    // ---- pass 1: load conf once, keep keys in registers, 14-bit histogram ----
    uint4 kk[MAXIT];
    #pragma unroll
    for (int it = 0; it < MAXIT; ++it) {
        const int m = tid * 4 + it * (NT * 4);
        if (m < M) {
            float4 c4 = *(const float4*)(confp + m);
            uint4 k4 = make_uint4(f2key(c4.x), f2key(c4.y), f2key(c4.z), f2key(c4.w));
            kk[it] = k4;
            atomicAdd(&s_hist[pbin(k4.x >> 18)], 1u);
            atomicAdd(&s_hist[pbin(k4.y >> 18)], 1u);
            atomicAdd(&s_hist[pbin(k4.z >> 18)], 1u);
            atomicAdd(&s_hist[pbin(k4.w >> 18)], 1u);
        }
    }
    __syncthreads();

    // ---- chunk totals (16 bins/thread, conflict-free reads) ----
    const int pb = tid * PADC;
    unsigned int ct = 0u;
    #pragma unroll
    for (int j = 0; j < BPT; ++j) ct += s_hist[pb + j];

    // in-wave inclusive suffix scan of chunk totals
    unsigned int sfx = ct;
    #pragma unroll
    for (int off = 1; off < 64; off <<= 1) {
        unsigned int v = __shfl_down(sfx, off, 64);
        if (lane + off < 64) sfx += v;
    }
    if (lane == 0) s_wtot[wid] = sfx;   // wave total
    __syncthreads();
    if (tid < NW) {
        unsigned int o = 0u;
        for (int j = tid + 1; j < NW; ++j) o += s_wtot[j];
        s_woff[tid] = o;                // sum of wave totals strictly above
    }
    __syncthreads();
    const unsigned int S_incl = sfx + s_woff[wid];   // count keys with bin >= tid*16
    const unsigned int right  = S_incl - ct;         // count keys with bin >= (tid+1)*16

    // crossing chunk -> crossing bin (scan own 16 bins from the top)
    if (right < TOPK && S_incl >= TOPK) {
        unsigned int cge = right;
        #pragma unroll
        for (int j = BPT - 1; j >= 0; --j) {
            cge += s_hist[pb + j];
            if (cge >= TOPK) { s_bin = (unsigned int)(tid * BPT + j); s_cntGe = cge; break; }
        }
    }
    __syncthreads();

    const unsigned int cntGe = s_cntGe;
    const unsigned int thr   = s_bin << 18;

    if (cntGe <= CAP) {
        // ---- compact candidates from register-held keys ----
        if (tid == 0) s_cnt = 0u;
        __syncthreads();
        #pragma unroll
        for (int it = 0; it < MAXIT; ++it) {
            const int m = tid * 4 + it * (NT * 4);
            if (m < M) {
                const uint4 k4 = kk[it];
                #pragma unroll
                for (int j = 0; j < 4; ++j) {
                    const unsigned int k = (j == 0) ? k4.x : (j == 1) ? k4.y
                                         : (j == 2) ? k4.z : k4.w;
                    if (k >= thr) {
                        unsigned int pos = atomicAdd(&s_cnt, 1u);
                        if (pos < CAP) {
                            s_candKey[pos] = k;
                            s_candIdx[pos] = (unsigned int)(m + j);
                        }
                    }
                }
            }
        }
        __syncthreads();
        const unsigned int cnt = s_cnt;
        // ---- rank-sort by (key desc, idx asc) — exact lax.top_k semantics ----
        for (int t = tid; t < (int)cnt; t += NT) {
            const unsigned long long p =
                ((unsigned long long)s_candKey[t] << 32) | (unsigned int)(~s_candIdx[t]);
            int rank = 0;
            for (unsigned int j = 0; j < cnt; ++j) {
                const unsigned long long q =
                    ((unsigned long long)s_candKey[j] << 32) | (unsigned int)(~s_candIdx[j]);
                rank += (q > p) ? 1 : 0;
            }
            if (rank < TOPK) { s_selKey[rank] = s_candKey[t]; s_selIdx[rank] = s_candIdx[t]; }
        }
        __syncthreads();
    } else {
        // ---- exact fallback (massive key ties; never expected) ----
        unsigned long long prev = 0xFFFFFFFFFFFFFFFFull;
        for (int i = 0; i < TOPK; ++i) {
            unsigned long long p = 0ull;
            #pragma unroll
            for (int it = 0; it < MAXIT; ++it) {
                const int m = tid * 4 + it * (NT * 4);
                if (m < M) {
                    const uint4 k4 = kk[it];
                    #pragma unroll
                    for (int j = 0; j < 4; ++j) {
                        const unsigned int k = (j == 0) ? k4.x : (j == 1) ? k4.y
                                             : (j == 2) ? k4.z : k4.w;
                        const unsigned long long pk =
                            ((unsigned long long)k << 32) |
                            (unsigned int)(~(unsigned int)(m + j));
                        if (pk < prev && pk > p) p = pk;
                    }
                }
            }
            #pragma unroll
            for (int off = 32; off > 0; off >>= 1) {
                unsigned long long q = __shfl_xor(p, off, 64);
                if (q > p) p = q;
            }
            if (lane == 0) s_wred[wid] = p;
            __syncthreads();
            if (tid == 0) {
                unsigned long long w = s_wred[0];
                #pragma unroll
                for (int j = 1; j < NW; ++j) if (s_wred[j] > w) w = s_wred[j];
                s_prev = w;
                s_selKey[i] = (unsigned int)(w >> 32);
                s_selIdx[i] = ~(unsigned int)w;
            }
            __syncthreads();
            prev = s_prev;
            __syncthreads();
        }
    }

    // ---- fused epilogue: one wave per output row ----
    const float* objp = a.obj[lvl];
    const float* actp = a.act[lvl];
    const float* relp = a.rel[lvl];
    const float* intp = a.intp[lvl];
    const float* regp = a.reg[lvl];

    for (int k = wid; k < TOPK; k += NW) {
        const unsigned int idx = s_selIdx[k];
        const float logit = key2f(s_selKey[k]);
        const float sc = 1.0f / (1.0f + expf(-logit));
        const float keep = (sc > 0.05f) ? 1.0f : 0.0f;

        float* orow = a.out + ((size_t)b * 150 + (size_t)lvl * TOPK + k) * NCH;
        const size_t rbase = (size_t)b * M + idx;

        // obj softmax over 36 classes (full-wave shuffle sum; lanes>=36 add 0)
        float e = 0.0f;
        if (lane < 36) e = expf(objp[rbase * 36 + lane]);
        float s = e;
        #pragma unroll
        for (int off = 32; off > 0; off >>= 1) s += __shfl_xor(s, off, 64);
        if (lane < 36) orow[6 + lane] = keep * (e / s);

        // act sigmoid (157)
        for (int c = lane; c < 157; c += 64) {
            float x = actp[rbase * 157 + c];
            orow[42 + c] = keep / (1.0f + expf(-x));
        }
        // rel sigmoid (26)
        if (lane < 26) {
            float x = relp[rbase * 26 + lane];
            orow[199 + lane] = keep / (1.0f + expf(-x));
        }
        // conf, inter, box
        if (lane == 0) {
            orow[4] = keep * sc;
            float xi = intp[rbase];
            orow[5] = keep / (1.0f + expf(-xi));
            const float r0 = regp[rbase * 4 + 0];
            const float r1 = regp[rbase * 4 + 1];
            const float r2 = regp[rbase * 4 + 2];
            const float r3 = regp[rbase * 4 + 3];
            const int yy = (int)idx / n;
            const int xx = (int)idx % n;
            const float fs = (float)stride;
            const float cx = (xx + 0.5f) * fs + r0 * fs;
            const float cy = (yy + 0.5f) * fs + r1 * fs;
            const float w2 = 0.5f * expf(r2) * fs;
            const float h2 = 0.5f * expf(r3) * fs;
            orow[0] = keep * (cx - w2);
            orow[1] = keep * (cy - h2);
            orow[2] = keep * (cx + w2);
            orow[3] = keep * (cy + h2);
        }
    }
}

extern "C" void kernel_launch(void* const* d_in, const int* in_sizes, int n_in,
                              void* d_out, int out_size, void* d_ws, size_t ws_size,
                              hipStream_t stream) {
    (void)in_sizes; (void)n_in; (void)out_size; (void)d_ws; (void)ws_size;
    Args a;
    for (int l = 0; l < 3; ++l) {
        a.conf[l] = (const float*)d_in[l * 6 + 0];
        a.obj[l]  = (const float*)d_in[l * 6 + 1];
        a.act[l]  = (const float*)d_in[l * 6 + 2];
        a.rel[l]  = (const float*)d_in[l * 6 + 3];
        a.intp[l] = (const float*)d_in[l * 6 + 4];
        a.reg[l]  = (const float*)d_in[l * 6 + 5];
    }
    a.out = (float*)d_out;
    hipLaunchKernelGGL(yowo_fused_kernel, dim3(96), dim3(NT), 0, stream, a);
}

// Round 5
// 19.648 us; speedup vs baseline: 17.5798x; 1.0609x over previous
//
#include <hip/hip_runtime.h>
#include <math.h>

#define TOPK 50
#define NCH 225
#define NBINS 16384
#define BPT 16              // bins per thread chunk (16384 / 1024)
#define PADC 17             // padded chunk stride (coprime with 32 banks)
#define CAP 1024
#define NT 1024
#define NW 16
#define MAXIT 2             // ceil(6400 / 4096)

// monotone float->uint key: preserves ordering, larger float -> larger key
__device__ __forceinline__ unsigned int f2key(float f) {
    unsigned int u = __float_as_uint(f);
    return (u & 0x80000000u) ? ~u : (u | 0x80000000u);
}
__device__ __forceinline__ float key2f(unsigned int k) {
    unsigned int u = (k & 0x80000000u) ? (k ^ 0x80000000u) : ~k;
    return __uint_as_float(u);
}
__device__ __forceinline__ int pbin(unsigned int bin) {
    return (int)((bin >> 4) * PADC + (bin & 15u));
}

struct ArgsA { const float* conf[3]; uint2* cand; };

struct ArgsB {
    const float* obj[3];
    const float* act[3];
    const float* rel[3];
    const float* intp[3];
    const float* reg[3];
    const uint2* cand;
    float* out;
};

// ---- Kernel A: exact top-50 of each chunk; lvl0 has 4 chunks of 6400 ----
__global__ __launch_bounds__(NT)
void yowo_select_kernel(ArgsA a) {
    __shared__ unsigned int s_hist[NT * PADC];     // 68 KB, pad-17 layout
    __shared__ unsigned int s_wtot[NW];
    __shared__ unsigned int s_woff[NW];
    __shared__ unsigned int s_candKey[CAP];
    __shared__ unsigned int s_candIdx[CAP];
    __shared__ unsigned int s_selKey[TOPK];
    __shared__ unsigned int s_selIdx[TOPK];
    __shared__ unsigned int s_cnt;
    __shared__ unsigned int s_bin, s_cntGe;
    __shared__ unsigned long long s_wred[NW];
    __shared__ unsigned long long s_prev;

    const int tid  = threadIdx.x;
    const int wid  = tid >> 6;
    const int lane = tid & 63;
    const int bid  = blockIdx.x;

    int lvl, b, c, Mc;
    if (bid < 128)      { lvl = 0; b = bid >> 2;  c = bid & 3; Mc = 6400; }
    else if (bid < 160) { lvl = 1; b = bid - 128; c = 0;       Mc = 6400; }
    else                { lvl = 2; b = bid - 160; c = 0;       Mc = 1600; }
    const int M    = (lvl == 0) ? 25600 : (lvl == 1) ? 6400 : 1600;
    const int base = c * 6400;
    const float* confp = a.conf[lvl] + (size_t)b * M + base;

    // zero padded histogram
    {
        const int zb = tid * PADC;
        #pragma unroll
        for (int j = 0; j < PADC; ++j) s_hist[zb + j] = 0u;
    }
    __syncthreads();

    // load chunk once, keys to registers, 14-bit histogram
    uint4 kk[MAXIT];
    #pragma unroll
    for (int it = 0; it < MAXIT; ++it) {
        const int m = tid * 4 + it * (NT * 4);
        if (m < Mc) {
            float4 c4 = *(const float4*)(confp + m);
            uint4 k4 = make_uint4(f2key(c4.x), f2key(c4.y), f2key(c4.z), f2key(c4.w));
            kk[it] = k4;
            atomicAdd(&s_hist[pbin(k4.x >> 18)], 1u);
            atomicAdd(&s_hist[pbin(k4.y >> 18)], 1u);
            atomicAdd(&s_hist[pbin(k4.z >> 18)], 1u);
            atomicAdd(&s_hist[pbin(k4.w >> 18)], 1u);
        }
    }
    __syncthreads();

    // chunk totals + hierarchical suffix scan
    const int pb = tid * PADC;
    unsigned int ct = 0u;
    #pragma unroll
    for (int j = 0; j < BPT; ++j) ct += s_hist[pb + j];
    unsigned int sfx = ct;
    #pragma unroll
    for (int off = 1; off < 64; off <<= 1) {
        unsigned int v = __shfl_down(sfx, off, 64);
        if (lane + off < 64) sfx += v;
    }
    if (lane == 0) s_wtot[wid] = sfx;
    __syncthreads();
    if (tid < NW) {
        unsigned int o = 0u;
        for (int j = tid + 1; j < NW; ++j) o += s_wtot[j];
        s_woff[tid] = o;
    }
    __syncthreads();
    const unsigned int S_incl = sfx + s_woff[wid];
    const unsigned int right  = S_incl - ct;

    if (right < TOPK && S_incl >= TOPK) {
        unsigned int cge = right;
        #pragma unroll
        for (int j = BPT - 1; j >= 0; --j) {
            cge += s_hist[pb + j];
            if (cge >= TOPK) { s_bin = (unsigned int)(tid * BPT + j); s_cntGe = cge; break; }
        }
    }
    __syncthreads();

    const unsigned int cntGe = s_cntGe;
    const unsigned int thr   = s_bin << 18;

    if (cntGe <= CAP) {
        if (tid == 0) s_cnt = 0u;
        __syncthreads();
        #pragma unroll
        for (int it = 0; it < MAXIT; ++it) {
            const int m = tid * 4 + it * (NT * 4);
            if (m < Mc) {
                const uint4 k4 = kk[it];
                #pragma unroll
                for (int j = 0; j < 4; ++j) {
                    const unsigned int k = (j == 0) ? k4.x : (j == 1) ? k4.y
                                         : (j == 2) ? k4.z : k4.w;
                    if (k >= thr) {
                        unsigned int pos = atomicAdd(&s_cnt, 1u);
                        if (pos < CAP) {
                            s_candKey[pos] = k;
                            s_candIdx[pos] = (unsigned int)(base + m + j);  // global idx
                        }
                    }
                }
            }
        }
        __syncthreads();
        const unsigned int cnt = s_cnt;
        for (int t = tid; t < (int)cnt; t += NT) {
            const unsigned long long p =
                ((unsigned long long)s_candKey[t] << 32) | (unsigned int)(~s_candIdx[t]);
            int rank = 0;
            for (unsigned int j = 0; j < cnt; ++j) {
                const unsigned long long q =
                    ((unsigned long long)s_candKey[j] << 32) | (unsigned int)(~s_candIdx[j]);
                rank += (q > p) ? 1 : 0;
            }
            if (rank < TOPK) { s_selKey[rank] = s_candKey[t]; s_selIdx[rank] = s_candIdx[t]; }
        }
        __syncthreads();
    } else {
        // exact fallback (massive key ties; never expected)
        unsigned long long prev = 0xFFFFFFFFFFFFFFFFull;
        for (int i = 0; i < TOPK; ++i) {
            unsigned long long p = 0ull;
            #pragma unroll
            for (int it = 0; it < MAXIT; ++it) {
                const int m = tid * 4 + it * (NT * 4);
                if (m < Mc) {
                    const uint4 k4 = kk[it];
                    #pragma unroll
                    for (int j = 0; j < 4; ++j) {
                        const unsigned int k = (j == 0) ? k4.x : (j == 1) ? k4.y
                                             : (j == 2) ? k4.z : k4.w;
                        const unsigned long long pk =
                            ((unsigned long long)k << 32) |
                            (unsigned int)(~(unsigned int)(base + m + j));
                        if (pk < prev && pk > p) p = pk;
                    }
                }
            }
            #pragma unroll
            for (int off = 32; off > 0; off >>= 1) {
                unsigned long long q = __shfl_xor(p, off, 64);
                if (q > p) p = q;
            }
            if (lane == 0) s_wred[wid] = p;
            __syncthreads();
            if (tid == 0) {
                unsigned long long w = s_wred[0];
                #pragma unroll
                for (int j = 1; j < NW; ++j) if (s_wred[j] > w) w = s_wred[j];
                s_prev = w;
                s_selKey[i] = (unsigned int)(w >> 32);
                s_selIdx[i] = ~(unsigned int)w;
            }
            __syncthreads();
            prev = s_prev;
            __syncthreads();
        }
    }

    if (tid < TOPK)
        a.cand[((size_t)((lvl * 32 + b) * 4 + c)) * TOPK + tid] =
            make_uint2(s_selKey[tid], s_selIdx[tid]);
}

// ---- Kernel B: redundant merge (<=200 cands) + disjoint epilogue slices ----
__global__ __launch_bounds__(NT)
void yowo_out_kernel(ArgsB a) {
    __shared__ unsigned int s_ck[200];
    __shared__ unsigned int s_ci[200];
    __shared__ unsigned int s_selKey[TOPK];
    __shared__ unsigned int s_selIdx[TOPK];

    const int tid  = threadIdx.x;
    const int wid  = tid >> 6;
    const int lane = tid & 63;
    const int grp  = blockIdx.x >> 2;   // 0..95  (lvl*32+b)
    const int sub  = blockIdx.x & 3;
    const int lvl  = grp >> 5;
    const int b    = grp & 31;

    const int M      = (lvl == 0) ? 25600 : (lvl == 1) ? 6400 : 1600;
    const int stride = 8 << lvl;
    const int n      = 1280 / stride;
    const int ncand  = (lvl == 0) ? 200 : TOPK;

    const uint2* cp = a.cand + (size_t)grp * 4 * TOPK;
    if (tid < ncand) {
        uint2 e = cp[tid];
        s_ck[tid] = e.x;
        s_ci[tid] = e.y;
    }
    __syncthreads();
    if (tid < ncand) {
        const unsigned long long p =
            ((unsigned long long)s_ck[tid] << 32) | (unsigned int)(~s_ci[tid]);
        int rank = 0;
        for (int j = 0; j < ncand; ++j) {
            const unsigned long long q =
                ((unsigned long long)s_ck[j] << 32) | (unsigned int)(~s_ci[j]);
            rank += (q > p) ? 1 : 0;
        }
        if (rank < TOPK) { s_selKey[rank] = s_ck[tid]; s_selIdx[rank] = s_ci[tid]; }
    }
    __syncthreads();

    // one gather-row per wave: k = sub + 4*wid
    const int k = sub + 4 * wid;
    if (k < TOPK) {
        const unsigned int idx = s_selIdx[k];
        const float logit = key2f(s_selKey[k]);
        const float sc   = 1.0f / (1.0f + expf(-logit));
        const float keep = (sc > 0.05f) ? 1.0f : 0.0f;

        float* orow = a.out + ((size_t)b * 150 + (size_t)lvl * TOPK + k) * NCH;
        const size_t rbase = (size_t)b * M + idx;

        // obj softmax over 36 classes
        float e = 0.0f;
        if (lane < 36) e = expf(a.obj[lvl][rbase * 36 + lane]);
        float s = e;
        #pragma unroll
        for (int off = 32; off > 0; off >>= 1) s += __shfl_xor(s, off, 64);
        if (lane < 36) orow[6 + lane] = keep * (e / s);

        // act sigmoid (157)
        #pragma unroll
        for (int c = lane; c < 157; c += 64) {
            float x = a.act[lvl][rbase * 157 + c];
            orow[42 + c] = keep / (1.0f + expf(-x));
        }
        // rel sigmoid (26)
        if (lane < 26) {
            float x = a.rel[lvl][rbase * 26 + lane];
            orow[199 + lane] = keep / (1.0f + expf(-x));
        }
        // conf, inter, box
        if (lane == 0) {
            orow[4] = keep * sc;
            float xi = a.intp[lvl][rbase];
            orow[5] = keep / (1.0f + expf(-xi));
            const float r0 = a.reg[lvl][rbase * 4 + 0];
            const float r1 = a.reg[lvl][rbase * 4 + 1];
            const float r2 = a.reg[lvl][rbase * 4 + 2];
            const float r3 = a.reg[lvl][rbase * 4 + 3];
            const int yy = (int)idx / n;
            const int xx = (int)idx % n;
            const float fs = (float)stride;
            const float cx = (xx + 0.5f) * fs + r0 * fs;
            const float cy = (yy + 0.5f) * fs + r1 * fs;
            const float w2 = 0.5f * expf(r2) * fs;
            const float h2 = 0.5f * expf(r3) * fs;
            orow[0] = keep * (cx - w2);
            orow[1] = keep * (cy - h2);
            orow[2] = keep * (cx + w2);
            orow[3] = keep * (cy + h2);
        }
    }
}

extern "C" void kernel_launch(void* const* d_in, const int* in_sizes, int n_in,
                              void* d_out, int out_size, void* d_ws, size_t ws_size,
                              hipStream_t stream) {
    (void)in_sizes; (void)n_in; (void)out_size; (void)ws_size;
    uint2* cand = (uint2*)d_ws;            // 96*4*50*8 = 153600 B

    ArgsA aa;
    ArgsB ab;
    for (int l = 0; l < 3; ++l) {
        aa.conf[l] = (const float*)d_in[l * 6 + 0];
        ab.obj[l]  = (const float*)d_in[l * 6 + 1];
        ab.act[l]  = (const float*)d_in[l * 6 + 2];
        ab.rel[l]  = (const float*)d_in[l * 6 + 3];
        ab.intp[l] = (const float*)d_in[l * 6 + 4];
        ab.reg[l]  = (const float*)d_in[l * 6 + 5];
    }
    aa.cand = cand;
    ab.cand = cand;
    ab.out  = (float*)d_out;

    hipLaunchKernelGGL(yowo_select_kernel, dim3(192), dim3(NT), 0, stream, aa);
    hipLaunchKernelGGL(yowo_out_kernel, dim3(384), dim3(NT), 0, stream, ab);
}